// Round 12
// baseline (903.798 us; speedup 1.0000x reference)
//
#include <hip/hip_runtime.h>
#include <hip/hip_bf16.h>

typedef __hip_bfloat16 bf16;
typedef __bf16 bh8 __attribute__((ext_vector_type(8)));
typedef float f32x4 __attribute__((ext_vector_type(4)));

#define BBATCH 256
#define NN   200
#define EE   1600

#define GLOAD16(gp, lp) __builtin_amdgcn_global_load_lds( \
    (const __attribute__((address_space(1))) void*)(gp),  \
    (__attribute__((address_space(3))) void*)(lp), 16, 0, 0)

__device__ inline float bf2f(bf16 v) { return __bfloat162float(v); }
__device__ inline float ldf(const float* p) { return *p; }
__device__ inline float ldf(const bf16* p) { return __bfloat162float(*p); }
__device__ inline void stf(float* p, float v) { *p = v; }
__device__ inline void stf(bf16* p, float v) { *p = __float2bfloat16(v); }

// ---------------- diagnostic (ws too small) ----------------
__global__ __launch_bounds__(256) void k_diag(float* out, int n, float v) {
    for (int i = blockIdx.x * 256 + threadIdx.x; i < n; i += gridDim.x * 256) out[i] = v;
}

// ---------------- degree / adjacency ----------------
__global__ __launch_bounds__(256) void k_deg(const int* __restrict__ ei, int* __restrict__ cnt) {
    int idx = blockIdx.x * 256 + threadIdx.x;           // B*E
    int b = idx / EE, e = idx % EE;
    int tg = ei[(long)b * 2 * EE + EE + e];
    atomicAdd(&cnt[b * NN + tg], 1);
}

__global__ __launch_bounds__(256) void k_dinv(const int* __restrict__ cnt, float* __restrict__ dinv) {
    int i = blockIdx.x * 256 + threadIdx.x;             // B*N
    dinv[i] = rsqrtf((float)cnt[i] + 1.0f);
}

__global__ __launch_bounds__(256) void k_adj(const int* __restrict__ ei, const float* __restrict__ dinv,
                                             float* __restrict__ AdjF) {
    int idx = blockIdx.x * 256 + threadIdx.x;           // B*E
    int b = idx / EE, e = idx % EE;
    const int* eb = ei + (long)b * 2 * EE;
    int s = eb[e], tg = eb[EE + e];
    // duplicate (s,tg) edges add IDENTICAL values -> order-independent -> deterministic
    atomicAdd(&AdjF[((long)b * NN + tg) * NN + s], dinv[b * NN + tg] * dinv[b * NN + s]);
}

__global__ __launch_bounds__(256) void k_adjself(const float* __restrict__ dinv, float* __restrict__ AdjF) {
    int idx = blockIdx.x * 256 + threadIdx.x;           // B*N
    int b = idx / NN, n = idx % NN;
    float d = dinv[idx];
    atomicAdd(&AdjF[((long)b * NN + n) * NN + n], d * d);
}

// AdjF [b][200][200] f32 -> Adjb [b][256][224] bf16 zero-padded
__global__ __launch_bounds__(256) void k_adjconv(const float* __restrict__ AdjF, bf16* __restrict__ Adjb) {
    long idx = (long)blockIdx.x * 256 + threadIdx.x;    // 256*256*224
    int col = idx % 224;
    int row = (idx / 224) & 255;
    int b = idx / (224 * 256);
    float v = (row < NN && col < NN) ? AdjF[((long)b * NN + row) * NN + col] : 0.f;
    Adjb[idx] = __float2bfloat16(v);
}

// m1t[b][h=256][node k=224] = (node_features @ W1)^T, zero-padded
__global__ __launch_bounds__(256) void k_m1t(const float* __restrict__ nf, const float* __restrict__ W1,
                                             bf16* __restrict__ m1t) {
    long idx = (long)blockIdx.x * 256 + threadIdx.x;    // 256*256*224
    int node = idx % 224;
    int h = (idx / 224) & 255;
    int b = idx / (224 * 256);
    float v = 0.f;
    if (node < NN) {
        const float* x = nf + ((long)b * NN + node) * 4;
        v = x[0] * W1[h] + x[1] * W1[256 + h] + x[2] * W1[512 + h] + x[3] * W1[768 + h];
    }
    m1t[idx] = __float2bfloat16(v);
}

// ---------------- weight conversions ----------------
__global__ __launch_bounds__(256) void k_conv(const float* __restrict__ s, bf16* __restrict__ d, int n) {
    int i = blockIdx.x * 256 + threadIdx.x;
    if (i < n) d[i] = __float2bfloat16(s[i]);
}

__global__ __launch_bounds__(256) void k_convT(const float* __restrict__ W2, bf16* __restrict__ w2t) {
    int i = blockIdx.x * 256 + threadIdx.x;             // 65536: i = n*256+k
    w2t[i] = __float2bfloat16(W2[((i & 255) << 8) + (i >> 8)]);
}

__global__ __launch_bounds__(256) void k_bsum(const float* __restrict__ bih, const float* __restrict__ bhh,
                                              float* __restrict__ bsum) {
    int i = blockIdx.x * 256 + threadIdx.x;             // 10240
    bsum[i] = bih[i] + bhh[i];
}

// ---- weight fragment shuffle: B-frag-contiguous, 16-wave layout ----
// dst[br][jw16][kc8][g4][lane64][8]  from Whh[br*2+layer]
__global__ __launch_bounds__(256) void k_wfrag(const float* __restrict__ Whh, bf16* __restrict__ dst_, int layer) {
    int i = blockIdx.x * 256 + threadIdx.x;             // < 163840
    int lane = i & 63, g = (i >> 6) & 3, kc = (i >> 8) & 7, jw = (i >> 11) & 15, br = i >> 15;
    int row = g * 256 + jw * 16 + (lane & 15);
    int col = kc * 32 + (lane >> 4) * 8;
    const float* src = Whh + (long)(br * 2 + layer) * 262144 + (long)row * 256 + col;
    bf16* dst = dst_ + (long)i * 8;
#pragma unroll
    for (int e = 0; e < 8; ++e) dst[e] = __float2bfloat16(src[e]);
}

// ---------------- MFMA GEMM: C = A @ Bt^T (+bias)(+relu), bf16 in/out, f32 accum ----------
template<int BM, int BN, bool RELU, bool CT>
__global__ __launch_bounds__(256)
void mgemm(const bf16* __restrict__ A, long aBatch, int lda,
           const bf16* __restrict__ Bt, long bBatch, int ldb,
           bf16* __restrict__ C, long cBatch, int ldc,
           const float* __restrict__ bias, long biasBatch,
           int K, int Mvalid)
{
    constexpr int ACH = BM / 16, TCH = BM / 16 + BN / 16, PW = TCH / 4;
    constexpr int FM = BM / 32, FN = BN / 32;
    __shared__ bf16 Al[BM][32];
    __shared__ bf16 Bl[BN][32];
    int bz = blockIdx.z;
    const bf16* Ab = A + (long)bz * aBatch + (long)blockIdx.y * BM * lda;
    const bf16* Bb = Bt + (long)bz * bBatch + (long)blockIdx.x * BN * ldb;
    int tid = threadIdx.x, w = tid >> 6, l = tid & 63;
    int wm = w >> 1, wn = w & 1;
    int lrow = l >> 2, lk8 = (l & 3) * 8;
    f32x4 acc[FM][FN] = {};
    for (int k0 = 0; k0 < K; k0 += 32) {
#pragma unroll
        for (int cc = 0; cc < PW; ++cc) {
            int c = w * PW + cc;
            if (c < ACH) GLOAD16(Ab + (long)(c * 16 + lrow) * lda + k0 + lk8, ((char*)&Al[0][0]) + c * 1024);
            else { int bc = c - ACH; GLOAD16(Bb + (long)(bc * 16 + lrow) * ldb + k0 + lk8, ((char*)&Bl[0][0]) + bc * 1024); }
        }
        __syncthreads();
        bh8 af[FM], bfv[FN];
#pragma unroll
        for (int i = 0; i < FM; ++i) af[i] = *(const bh8*)&Al[wm * (BM / 2) + i * 16 + (l & 15)][(l >> 4) * 8];
#pragma unroll
        for (int j = 0; j < FN; ++j) bfv[j] = *(const bh8*)&Bl[wn * (BN / 2) + j * 16 + (l & 15)][(l >> 4) * 8];
#pragma unroll
        for (int i = 0; i < FM; ++i)
#pragma unroll
            for (int j = 0; j < FN; ++j)
                acc[i][j] = __builtin_amdgcn_mfma_f32_16x16x32_bf16(af[i], bfv[j], acc[i][j], 0, 0, 0);
        __syncthreads();
    }
    bf16* Cb = C + (long)bz * cBatch;
    int mq = blockIdx.y * BM + wm * (BM / 2);
    int nq = blockIdx.x * BN + wn * (BN / 2);
#pragma unroll
    for (int i = 0; i < FM; ++i) {
#pragma unroll
        for (int j = 0; j < FN; ++j) {
            int n = nq + j * 16 + (l & 15);
            float bv = bias ? bias[(long)bz * biasBatch + n] : 0.f;
            int m0 = mq + i * 16 + (l >> 4) * 4;
#pragma unroll
            for (int r = 0; r < 4; ++r) {
                int m = m0 + r;
                if (m < Mvalid) {
                    float v = acc[i][j][r] + bv;
                    if (RELU) v = fmaxf(v, 0.f);
                    if (CT) Cb[(long)n * ldc + m] = __float2bfloat16(v);
                    else    Cb[(long)m * ldc + n] = __float2bfloat16(v);
                }
            }
        }
    }
}

// ============ persistent block-local LSTM layer 0, weight-resident ============
// 80 blocks, XCD-pinned; 1024 thr = 16 waves (4/SIMD -> 128 VGPR budget).
// Weights: kc 0..3 pinned in VGPR (64 regs; "+v" asm blocks rematerialization),
// kc 4..5 in LDS (128 KB), kc 6..7 streamed from L2 (128 KB/step/CU).
__global__ __launch_bounds__(1024, 4)
void k_rnn0(const bf16* __restrict__ wfrag0, const bf16* __restrict__ gpart,
            const float* __restrict__ xf, const float* __restrict__ wih0,
            bf16* __restrict__ y0)
{
    extern __shared__ char dyns[];              // [0,131072) weights kc4..5; [131072,147456) hbuf
    char* wlds = dyns;
    char* hbase = dyns + 131072;
    int g_ = 10 * (blockIdx.x & 7) + (blockIdx.x >> 3);   // XCD-pinning permutation
    int btile = g_ & 15, br = g_ >> 4;
    int tid = threadIdx.x, w = tid >> 6, l = tid & 63;
    int ln = l & 15, lg = l >> 4;
    int j = w * 16 + ln;
    const bf16* wb = wfrag0 + ((long)(br * 16 + w)) * 16384 + l * 8;
    // VGPR-resident weights (kc 0..3)
    bh8 wreg[16];
#pragma unroll
    for (int kc = 0; kc < 4; ++kc)
#pragma unroll
        for (int g = 0; g < 4; ++g)
            wreg[kc * 4 + g] = *(const bh8*)(wb + kc * 2048 + g * 512);
    // pretend wb changed (VGPR pair constraint — wb is lane-varying):
    // the compiler can no longer rematerialize wreg from memory
    asm volatile("" : "+v"(wb));
    // LDS-resident weights (kc 4..5): lane-linear 16B layout (conflict-free)
#pragma unroll
    for (int f = 0; f < 8; ++f) {
        int kc = 4 + (f >> 2), g = f & 3;
        *(uint4*)(wlds + (w * 8 + f) * 1024 + l * 16) = *(const uint4*)(wb + kc * 2048 + g * 512);
    }
    // packed per-thread constants
    __hip_bfloat162 w01p[4];
    __hip_bfloat162 gpk[8];                     // [g][rpair]
#pragma unroll
    for (int g = 0; g < 4; ++g) {
        const float* wr = wih0 + ((long)br * 1024 + g * 256 + j) * 258;
        w01p[g].x = __float2bfloat16(wr[0]);
        w01p[g].y = __float2bfloat16(wr[1]);
#pragma unroll
        for (int rp = 0; rp < 2; ++rp) {
            int b0 = btile * 16 + lg * 4 + rp * 2;
            __hip_bfloat162 t2;
            t2.x = gpart[((long)br * 256 + b0) * 1024 + g * 256 + j];
            t2.y = gpart[((long)br * 256 + b0 + 1) * 1024 + g * 256 + j];
            gpk[g * 2 + rp] = t2;
        }
    }
    float c[4] = {};
    __syncthreads();
    int pp = 0;
#pragma unroll 1
    for (int t = 0; t < 30; ++t) {
        f32x4 acc[4] = {};
        if (t > 0) {
            const char* hb = hbase + (pp ^ 1) * 8192;
#pragma unroll
            for (int kc = 0; kc < 4; ++kc) {    // VGPR weights
                bh8 a = *(const bh8*)(hb + ln * 512 + ((kc * 64 + lg * 16) ^ ((ln & 7) << 4)));
#pragma unroll
                for (int g = 0; g < 4; ++g)
                    acc[g] = __builtin_amdgcn_mfma_f32_16x16x32_bf16(a, wreg[kc * 4 + g], acc[g], 0, 0, 0);
            }
#pragma unroll
            for (int kc = 4; kc < 6; ++kc) {    // LDS weights
                bh8 a = *(const bh8*)(hb + ln * 512 + ((kc * 64 + lg * 16) ^ ((ln & 7) << 4)));
#pragma unroll
                for (int g = 0; g < 4; ++g) {
                    bh8 wv = *(const bh8*)(wlds + (w * 8 + (kc - 4) * 4 + g) * 1024 + l * 16);
                    acc[g] = __builtin_amdgcn_mfma_f32_16x16x32_bf16(a, wv, acc[g], 0, 0, 0);
                }
            }
#pragma unroll
            for (int kc = 6; kc < 8; ++kc) {    // streamed weights (L2)
                bh8 a = *(const bh8*)(hb + ln * 512 + ((kc * 64 + lg * 16) ^ ((ln & 7) << 4)));
#pragma unroll
                for (int g = 0; g < 4; ++g) {
                    bh8 wv = *(const bh8*)(wb + kc * 2048 + g * 512);
                    acc[g] = __builtin_amdgcn_mfma_f32_16x16x32_bf16(a, wv, acc[g], 0, 0, 0);
                }
            }
        }
        char* hw = hbase + pp * 8192;
        float2 xr[4];
#pragma unroll
        for (int r = 0; r < 4; ++r) {
            int b = btile * 16 + lg * 4 + r;
            xr[r] = *(const float2*)(xf + ((long)(br * 256 + b) * 30 + t) * 2);
        }
#pragma unroll
        for (int r = 0; r < 4; ++r) {
            float z[4];
#pragma unroll
            for (int g = 0; g < 4; ++g) {
                __hip_bfloat162 gp2 = gpk[g * 2 + (r >> 1)];
                float gpv = (r & 1) ? __high2float(gp2) : __low2float(gp2);
                z[g] = acc[g][r] + gpv + xr[r].x * __low2float(w01p[g]) + xr[r].y * __high2float(w01p[g]);
            }
            float ig = 1.f / (1.f + __expf(-z[0]));
            float fg = 1.f / (1.f + __expf(-z[1]));
            float gv = 2.f / (1.f + __expf(-2.f * z[2])) - 1.f;
            float og = 1.f / (1.f + __expf(-z[3]));
            float cv = fg * c[r] + ig * gv;
            c[r] = cv;
            float hv = og * (2.f / (1.f + __expf(-2.f * cv)) - 1.f);
            int row = lg * 4 + r;
            *(bf16*)(hw + row * 512 + ((2 * j) ^ ((row & 7) << 4))) = __float2bfloat16(hv);
        }
        __syncthreads();
        // unswizzling coalesced copy of the h tile -> y0[t] (8 KB, 8 B/thread)
        {
            int row = tid >> 6;
            int off = (tid & 63) * 8;
            uint2 v = *(const uint2*)(hw + row * 512 + (off ^ ((row & 7) << 4)));
            *(uint2*)((char*)y0 + (((long)(br * 30 + t) * 256 + btile * 16 + row) * 512) + off) = v;
        }
        pp ^= 1;
    }
}

// ============ persistent block-local LSTM layer 1, weight-resident (K=256) ============
// zin1 precomputed by mgemm (incl. bias). Same weight residency scheme as k_rnn0.
__global__ __launch_bounds__(1024, 4)
void k_rnn1(const bf16* __restrict__ wfrag1, const bf16* __restrict__ zin1,
            bf16* __restrict__ h1out)
{
    extern __shared__ char dyns[];
    char* wlds = dyns;
    char* hbase = dyns + 131072;
    int g_ = 10 * (blockIdx.x & 7) + (blockIdx.x >> 3);   // XCD-pinning permutation
    int btile = g_ & 15, br = g_ >> 4;
    int tid = threadIdx.x, w = tid >> 6, l = tid & 63;
    int ln = l & 15, lg = l >> 4;
    int j = w * 16 + ln;
    const bf16* wb = wfrag1 + ((long)(br * 16 + w)) * 16384 + l * 8;
    bh8 wreg[16];
#pragma unroll
    for (int kc = 0; kc < 4; ++kc)
#pragma unroll
        for (int g = 0; g < 4; ++g)
            wreg[kc * 4 + g] = *(const bh8*)(wb + kc * 2048 + g * 512);
    asm volatile("" : "+v"(wb));
#pragma unroll
    for (int f = 0; f < 8; ++f) {
        int kc = 4 + (f >> 2), g = f & 3;
        *(uint4*)(wlds + (w * 8 + f) * 1024 + l * 16) = *(const uint4*)(wb + kc * 2048 + g * 512);
    }
    float c[4] = {};
    __syncthreads();
    int pp = 0;
    const bf16* zbr = zin1 + (long)br * 7864320;
#pragma unroll 1
    for (int t = 0; t < 30; ++t) {
        // zin for this step (includes bias) — issued first to hide L2 latency
        float zin[4][4];                                  // [g][r]
#pragma unroll
        for (int r = 0; r < 4; ++r) {
            long mrow = (long)(t * 256 + btile * 16 + lg * 4 + r) * 1024;
#pragma unroll
            for (int g = 0; g < 4; ++g) zin[g][r] = bf2f(zbr[mrow + g * 256 + j]);
        }
        f32x4 acc[4] = {};
        if (t > 0) {
            const char* hb = hbase + (pp ^ 1) * 8192;
#pragma unroll
            for (int kc = 0; kc < 4; ++kc) {
                bh8 a = *(const bh8*)(hb + ln * 512 + ((kc * 64 + lg * 16) ^ ((ln & 7) << 4)));
#pragma unroll
                for (int g = 0; g < 4; ++g)
                    acc[g] = __builtin_amdgcn_mfma_f32_16x16x32_bf16(a, wreg[kc * 4 + g], acc[g], 0, 0, 0);
            }
#pragma unroll
            for (int kc = 4; kc < 6; ++kc) {
                bh8 a = *(const bh8*)(hb + ln * 512 + ((kc * 64 + lg * 16) ^ ((ln & 7) << 4)));
#pragma unroll
                for (int g = 0; g < 4; ++g) {
                    bh8 wv = *(const bh8*)(wlds + (w * 8 + (kc - 4) * 4 + g) * 1024 + l * 16);
                    acc[g] = __builtin_amdgcn_mfma_f32_16x16x32_bf16(a, wv, acc[g], 0, 0, 0);
                }
            }
#pragma unroll
            for (int kc = 6; kc < 8; ++kc) {
                bh8 a = *(const bh8*)(hb + ln * 512 + ((kc * 64 + lg * 16) ^ ((ln & 7) << 4)));
#pragma unroll
                for (int g = 0; g < 4; ++g) {
                    bh8 wv = *(const bh8*)(wb + kc * 2048 + g * 512);
                    acc[g] = __builtin_amdgcn_mfma_f32_16x16x32_bf16(a, wv, acc[g], 0, 0, 0);
                }
            }
        }
        char* hw = hbase + pp * 8192;
#pragma unroll
        for (int r = 0; r < 4; ++r) {
            float z[4];
#pragma unroll
            for (int g = 0; g < 4; ++g) z[g] = acc[g][r] + zin[g][r];
            float ig = 1.f / (1.f + __expf(-z[0]));
            float fg = 1.f / (1.f + __expf(-z[1]));
            float gv = 2.f / (1.f + __expf(-2.f * z[2])) - 1.f;
            float og = 1.f / (1.f + __expf(-z[3]));
            float cv = fg * c[r] + ig * gv;
            c[r] = cv;
            float hv = og * (2.f / (1.f + __expf(-2.f * cv)) - 1.f);
            int row = lg * 4 + r;
            *(bf16*)(hw + row * 512 + ((2 * j) ^ ((row & 7) << 4))) = __float2bfloat16(hv);
            if (t == 29) {
                int b = btile * 16 + row;
                h1out[((long)br * 256 + b) * 256 + j] = __float2bfloat16(hv);
            }
        }
        __syncthreads();
        pp ^= 1;
    }
}

// ---------------- small f32 GEMM (tiny gfeat/gpart) ----------------
template <bool BT, typename TA, typename TB, typename TC>
__global__ __launch_bounds__(256)
void gemm64(const TA* __restrict__ A, long aBatch, int lda,
            const TB* __restrict__ Bm, long bBatch, int ldb,
            TC* __restrict__ C, long cBatch, int ldc,
            const float* __restrict__ bias, long biasBatch,
            int M, int Nn, int K, int flags) {
    __shared__ float As[16][64];
    __shared__ float Bs[16][64];
    int bz = blockIdx.z;
    const TA* Ab = A + (long)bz * aBatch;
    const TB* Bb = Bm + (long)bz * bBatch;
    TC* Cb = C + (long)bz * cBatch;
    int m0 = blockIdx.y * 64, n0 = blockIdx.x * 64;
    int tid = threadIdx.x;
    int tr = tid >> 4, tc = tid & 15;
    float acc[4][4] = {};
    int la_m = tid >> 2;
    int la_k = (tid & 3) * 4;
    for (int k0 = 0; k0 < K; k0 += 16) {
#pragma unroll
        for (int j = 0; j < 4; ++j) {
            int kk = la_k + j;
            float v = 0.f;
            if (m0 + la_m < M && k0 + kk < K) v = ldf(&Ab[(long)(m0 + la_m) * lda + k0 + kk]);
            As[kk][la_m] = v;
        }
        if (!BT) {
            int n = tid & 63, kb = (tid >> 6) * 4;
#pragma unroll
            for (int j = 0; j < 4; ++j) {
                int kk = kb + j;
                float v = 0.f;
                if (k0 + kk < K && n0 + n < Nn) v = ldf(&Bb[(long)(k0 + kk) * ldb + n0 + n]);
                Bs[kk][n] = v;
            }
        } else {
            int n = tid >> 2, kb = (tid & 3) * 4;
#pragma unroll
            for (int j = 0; j < 4; ++j) {
                int kk = kb + j;
                float v = 0.f;
                if (k0 + kk < K && n0 + n < Nn) v = ldf(&Bb[(long)(n0 + n) * ldb + k0 + kk]);
                Bs[kk][n] = v;
            }
        }
        __syncthreads();
#pragma unroll
        for (int kk = 0; kk < 16; ++kk) {
            float4 a4 = *(const float4*)&As[kk][tr * 4];
            float4 b4 = *(const float4*)&Bs[kk][tc * 4];
            float a[4] = {a4.x, a4.y, a4.z, a4.w};
            float bb[4] = {b4.x, b4.y, b4.z, b4.w};
#pragma unroll
            for (int i = 0; i < 4; ++i)
#pragma unroll
                for (int j = 0; j < 4; ++j) acc[i][j] += a[i] * bb[j];
        }
        __syncthreads();
    }
#pragma unroll
    for (int i = 0; i < 4; ++i) {
        int m = m0 + tr * 4 + i;
        if (m >= M) continue;
#pragma unroll
        for (int j = 0; j < 4; ++j) {
            int n = n0 + tc * 4 + j;
            if (n >= Nn) continue;
            float v = acc[i][j];
            if (bias) v += bias[(long)bz * biasBatch + n];
            if (flags & 1) v = fmaxf(v, 0.f);
            stf(&Cb[(long)m * ldc + n], v);
        }
    }
}

// ---------------- MFMA attention, fully reduced to gmean ----------------
__global__ __launch_bounds__(256) void k_attn(const bf16* __restrict__ qkv, float* __restrict__ gmean) {
    int b = blockIdx.x >> 2, hd = blockIdx.x & 3;
    __shared__ bf16 Ks[208][72];
    __shared__ float CSl[4][208];
    __shared__ float Gp[4][64];
    int tid = threadIdx.x, w = tid >> 6, l = tid & 63;
    const bf16* qb = qkv + (long)b * (NN * 768) + hd * 64;
    for (int i = tid; i < 208 * 8; i += 256) {
        int n = i >> 3, g = i & 7;
        uint4 v = make_uint4(0, 0, 0, 0);
        if (n < NN) v = *(const uint4*)(qb + (long)n * 768 + 256 + g * 8);
        *(uint4*)&Ks[n][g * 8] = v;
    }
    __syncthreads();
    float cs[13];
#pragma unroll
    for (int t = 0; t < 13; ++t) cs[t] = 0.f;
    int ln = l & 15, lg = l >> 4;
    for (int qt = w; qt < 13; qt += 4) {
        int qr = qt * 16 + ln; if (qr > NN - 1) qr = NN - 1;
        bh8 aq0 = *(const bh8*)(qb + (long)qr * 768 + lg * 8);
        bh8 aq1 = *(const bh8*)(qb + (long)qr * 768 + 32 + lg * 8);
        f32x4 s[13];
#pragma unroll
        for (int t = 0; t < 13; ++t) s[t] = f32x4{0.f, 0.f, 0.f, 0.f};
#pragma unroll
        for (int t = 0; t < 13; ++t) {
            bh8 b0 = *(const bh8*)&Ks[t * 16 + ln][lg * 8];
            bh8 b1 = *(const bh8*)&Ks[t * 16 + ln][32 + lg * 8];
            s[t] = __builtin_amdgcn_mfma_f32_16x16x32_bf16(aq0, b0, s[t], 0, 0, 0);
            s[t] = __builtin_amdgcn_mfma_f32_16x16x32_bf16(aq1, b1, s[t], 0, 0, 0);
        }
        float mx[4] = {-1e30f, -1e30f, -1e30f, -1e30f};
#pragma unroll
        for (int t = 0; t < 13; ++t) {
            bool vn = (t < 12) | (ln < 8);
#pragma unroll
            for (int r = 0; r < 4; ++r) {
                float v = s[t][r] * 0.125f;
                s[t][r] = v;
                if (vn) mx[r] = fmaxf(mx[r], v);
            }
        }
#pragma unroll
        for (int off = 1; off < 16; off <<= 1)
#pragma unroll
            for (int r = 0; r < 4; ++r) mx[r] = fmaxf(mx[r], __shfl_xor(mx[r], off));
        float sum[4] = {0.f, 0.f, 0.f, 0.f};
#pragma unroll
        for (int t = 0; t < 13; ++t) {
            bool vn = (t < 12) | (ln < 8);
#pragma unroll
            for (int r = 0; r < 4; ++r) {
                float e = vn ? __expf(s[t][r] - mx[r]) : 0.f;
                s[t][r] = e;
                sum[r] += e;
            }
        }
#pragma unroll
        for (int off = 1; off < 16; off <<= 1)
#pragma unroll
            for (int r = 0; r < 4; ++r) sum[r] += __shfl_xor(sum[r], off);
        float inv[4];
#pragma unroll
        for (int r = 0; r < 4; ++r) inv[r] = 1.f / sum[r];
#pragma unroll
        for (int r = 0; r < 4; ++r) {
            int q = qt * 16 + lg * 4 + r;
            if (q < NN) {
#pragma unroll
                for (int t = 0; t < 13; ++t) cs[t] += s[t][r] * inv[r];
            }
        }
    }
#pragma unroll
    for (int t = 0; t < 13; ++t) {
        cs[t] += __shfl_xor(cs[t], 16);
        cs[t] += __shfl_xor(cs[t], 32);
    }
    if (l < 16) {
#pragma unroll
        for (int t = 0; t < 13; ++t) CSl[w][t * 16 + l] = cs[t];
    }
    __syncthreads();
    float part = 0.f;
    for (int n = w * 50; n < w * 50 + 50; ++n) {
        float csn = CSl[0][n] + CSl[1][n] + CSl[2][n] + CSl[3][n];
        part += csn * bf2f(qb[(long)n * 768 + 512 + l]);
    }
    Gp[w][l] = part;
    __syncthreads();
    if (w == 0) {
        float tot = Gp[0][l] + Gp[1][l] + Gp[2][l] + Gp[3][l];
        gmean[b * 256 + hd * 64 + l] = tot * (1.0f / 200.0f);
    }
}

// ---------------- heads ----------------
__global__ __launch_bounds__(256) void k_heads(const bf16* __restrict__ lasth,
                                               const float* __restrict__ fcW_pv, const float* __restrict__ fcb_pv,
                                               const float* __restrict__ fcW_s, const float* __restrict__ fcb_s,
                                               float* __restrict__ out) {
    int b = blockIdx.x;
    __shared__ float hl[5][257];
    for (int idx = threadIdx.x; idx < 5 * 256; idx += 256) {
        int k = idx >> 8, h = idx & 255;
        hl[k][h] = bf2f(lasth[((long)k * 256 + b) * 256 + h]);
    }
    __syncthreads();
    int i = threadIdx.x;
    if (i < 210) {
        int k, o, l, c;
        const float* w;
        float bias;
        bool sig = false;
        if (i < 60)       { k = 0; o = i;       w = fcW_pv + o * 256;        bias = fcb_pv[o];       l = o >> 1; c = o & 1; }
        else if (i < 120) { k = 1; o = i - 60;  w = fcW_pv + (60 + o) * 256; bias = fcb_pv[60 + o];  l = o >> 1; c = 2 + (o & 1); }
        else if (i < 150) { k = 2; o = i - 120; w = fcW_s + o * 256;         bias = fcb_s[o];        l = o; c = 4; }
        else if (i < 180) { k = 3; o = i - 150; w = fcW_s + (30 + o) * 256;  bias = fcb_s[30 + o];   l = o; c = 5; sig = true; }
        else              { k = 4; o = i - 180; w = fcW_s + (60 + o) * 256;  bias = fcb_s[60 + o];   l = o; c = 6; sig = true; }
        float acc = bias;
        for (int h = 0; h < 256; ++h) acc += hl[k][h] * w[h];
        if (sig) acc = 1.f / (1.f + __expf(-acc));
        out[(long)b * 210 + l * 7 + c] = acc;
    }
}

// ---------------- launch ----------------
extern "C" void kernel_launch(void* const* d_in, const int* in_sizes, int n_in,
                              void* d_out, int out_size, void* d_ws, size_t ws_size,
                              hipStream_t stream) {
    (void)in_sizes; (void)n_in;
    const float* x_feats   = (const float*)d_in[0];
    const float* node_feat = (const float*)d_in[1];
    const int*   edge_idx  = (const int*)d_in[2];
    const float* gcn_W1    = (const float*)d_in[3];
    const float* gcn_b1    = (const float*)d_in[4];
    const float* gcn_W2    = (const float*)d_in[5];
    const float* gcn_b2    = (const float*)d_in[6];
    const float* attn_in_w = (const float*)d_in[7];
    const float* attn_in_b = (const float*)d_in[8];
    const float* attn_out_w= (const float*)d_in[9];
    const float* attn_out_b= (const float*)d_in[10];
    const float* Wih0      = (const float*)d_in[11];
    const float* Wih1      = (const float*)d_in[12];
    const float* Whh       = (const float*)d_in[13];
    const float* bih       = (const float*)d_in[14];
    const float* bhh       = (const float*)d_in[15];
    const float* fcW_pv    = (const float*)d_in[16];
    const float* fcb_pv    = (const float*)d_in[17];
    const float* fcW_s     = (const float*)d_in[18];
    const float* fcb_s     = (const float*)d_in[19];
    float* out = (float*)d_out;

    const size_t NEEDED = 186966016ULL;
    if (ws_size < NEEDED) {
        k_diag<<<210, 256, 0, stream>>>(out, out_size, (float)(ws_size >> 20));
        return;
    }
    char* base = (char*)d_ws;
    bf16*  Adjb  = (bf16*)(base + 0);            // [256][256][224]
    bf16*  y0    = (bf16*)(base + 0);            // [5][30][256][256] plain rows (Adjb dead)
    bf16*  m1t   = (bf16*)(base + 29360128);     // [256][256][224] (later m2t)
    bf16*  m2t   = m1t;
    bf16*  actp  = (bf16*)(base + 58720256);     // [256][256][256] (h1p -> gp)
    char*  bigb  = base + 92274688;              // AdjF f32 -> qkv -> zin1
    float* AdjF  = (float*)bigb;
    bf16*  qkv   = (bf16*)bigb;
    bf16*  zin1  = (bf16*)bigb;                  // [5][7680][1024]
    bf16*  w2t   = (bf16*)(base + 170917888);
    bf16*  aiwb  = (bf16*)(base + 171048960);
    bf16*  wih1b = (bf16*)(base + 171442176);
    bf16*  wfrag0= (bf16*)(base + 174063616);
    bf16*  wfrag1= (bf16*)(base + 176685056);
    bf16*  gpart = (bf16*)(base + 179306496);
    float* dinv  = (float*)(base + 181927936);
    int*   degc  = (int*)(base + 182132736);
    float* gmean = (float*)(base + 182337536);
    float* gfeat = (float*)(base + 182599680);
    float* bsum  = (float*)(base + 182861824);
    bf16*  h1b   = (bf16*)(base + 186310656);

    hipMemsetAsync(AdjF, 0, 40960000, stream);
    hipMemsetAsync(degc, 0, 204800, stream);

    k_deg<<<1600, 256, 0, stream>>>(edge_idx, degc);
    k_dinv<<<200, 256, 0, stream>>>(degc, dinv);
    k_adj<<<1600, 256, 0, stream>>>(edge_idx, dinv, AdjF);
    k_adjself<<<200, 256, 0, stream>>>(dinv, AdjF);
    k_adjconv<<<57344, 256, 0, stream>>>(AdjF, Adjb);
    k_m1t<<<57344, 256, 0, stream>>>(node_feat, gcn_W1, m1t);

    k_convT<<<256, 256, 0, stream>>>(gcn_W2, w2t);
    k_conv<<<768, 256, 0, stream>>>(attn_in_w, aiwb, 196608);
    k_conv<<<5120, 256, 0, stream>>>(Wih1, wih1b, 1310720);
    k_wfrag<<<640, 256, 0, stream>>>(Whh, wfrag0, 0);
    k_wfrag<<<640, 256, 0, stream>>>(Whh, wfrag1, 1);
    k_bsum<<<40, 256, 0, stream>>>(bih, bhh, bsum);

    mgemm<128, 128, true, false><<<dim3(2, 2, 256), 256, 0, stream>>>(
        Adjb, 57344, 224, m1t, 57344, 224, actp, 65536, 256, gcn_b1, 0, 224, 256);
    mgemm<128, 128, false, true><<<dim3(2, 2, 256), 256, 0, stream>>>(
        actp, 65536, 256, w2t, 0, 256, m2t, 57344, 224, nullptr, 0, 256, 200);
    mgemm<128, 128, true, false><<<dim3(2, 2, 256), 256, 0, stream>>>(
        Adjb, 57344, 224, m2t, 57344, 224, actp, 65536, 256, gcn_b2, 0, 224, 256);
    mgemm<128, 128, false, false><<<dim3(6, 2, 256), 256, 0, stream>>>(
        actp, 65536, 256, aiwb, 0, 256, qkv, 153600, 768, attn_in_b, 0, 256, 200);

    k_attn<<<1024, 256, 0, stream>>>(qkv, gmean);
    gemm64<true, float, float, float><<<dim3(4, 4, 1), 256, 0, stream>>>(
        gmean, 0, 256, attn_out_w, 0, 256, gfeat, 0, 256, attn_out_b, 0, 256, 256, 256, 0);
    gemm64<true, float, float, bf16><<<dim3(16, 4, 5), 256, 0, stream>>>(
        gfeat, 0, 256, Wih0 + 2, 264192, 258, gpart, 262144, 1024, bsum, 2048, 256, 1024, 256, 0);

    // weight-resident persistent LSTM layers (147456 B dynamic LDS each)
    hipFuncSetAttribute((const void*)k_rnn0, hipFuncAttributeMaxDynamicSharedMemorySize, 147456);
    hipFuncSetAttribute((const void*)k_rnn1, hipFuncAttributeMaxDynamicSharedMemorySize, 147456);
    k_rnn0<<<80, 1024, 147456, stream>>>(wfrag0, gpart, x_feats, Wih0, y0);
    mgemm<128, 128, false, false><<<dim3(8, 60, 5), 256, 0, stream>>>(
        y0, 1966080, 256, wih1b, 262144, 256, zin1, 7864320, 1024, bsum + 1024, 2048, 256, 7680);
    k_rnn1<<<80, 1024, 147456, stream>>>(wfrag1, zin1, h1b);
    k_heads<<<256, 256, 0, stream>>>(h1b, fcW_pv, fcb_pv, fcW_s, fcb_s, out);
}

// Round 14
// 898.874 us; speedup vs baseline: 1.0055x; 1.0055x over previous
//
#include <hip/hip_runtime.h>
#include <hip/hip_bf16.h>

typedef __hip_bfloat16 bf16;
typedef __bf16 bh8 __attribute__((ext_vector_type(8)));
typedef float f32x4 __attribute__((ext_vector_type(4)));

#define BBATCH 256
#define NN   200
#define EE   1600

#define GLOAD16(gp, lp) __builtin_amdgcn_global_load_lds( \
    (const __attribute__((address_space(1))) void*)(gp),  \
    (__attribute__((address_space(3))) void*)(lp), 16, 0, 0)

__device__ inline float bf2f(bf16 v) { return __bfloat162float(v); }
__device__ inline float ldf(const float* p) { return *p; }
__device__ inline float ldf(const bf16* p) { return __bfloat162float(*p); }
__device__ inline void stf(float* p, float v) { *p = v; }
__device__ inline void stf(bf16* p, float v) { *p = __float2bfloat16(v); }

// pin a 16-byte fragment's VALUE in VGPRs via four scalar reg ties:
// after this the compiler cannot rematerialize the fragment from memory.
__device__ inline void pin16(bh8* v) {
    unsigned int t0, t1, t2, t3;
    __builtin_memcpy(&t0, (char*)v + 0, 4);
    __builtin_memcpy(&t1, (char*)v + 4, 4);
    __builtin_memcpy(&t2, (char*)v + 8, 4);
    __builtin_memcpy(&t3, (char*)v + 12, 4);
    asm volatile("" : "+v"(t0), "+v"(t1), "+v"(t2), "+v"(t3));
    __builtin_memcpy((char*)v + 0, &t0, 4);
    __builtin_memcpy((char*)v + 4, &t1, 4);
    __builtin_memcpy((char*)v + 8, &t2, 4);
    __builtin_memcpy((char*)v + 12, &t3, 4);
}

// ---------------- diagnostic (ws too small) ----------------
__global__ __launch_bounds__(256) void k_diag(float* out, int n, float v) {
    for (int i = blockIdx.x * 256 + threadIdx.x; i < n; i += gridDim.x * 256) out[i] = v;
}

// ---------------- degree / adjacency ----------------
__global__ __launch_bounds__(256) void k_deg(const int* __restrict__ ei, int* __restrict__ cnt) {
    int idx = blockIdx.x * 256 + threadIdx.x;           // B*E
    int b = idx / EE, e = idx % EE;
    int tg = ei[(long)b * 2 * EE + EE + e];
    atomicAdd(&cnt[b * NN + tg], 1);
}

__global__ __launch_bounds__(256) void k_dinv(const int* __restrict__ cnt, float* __restrict__ dinv) {
    int i = blockIdx.x * 256 + threadIdx.x;             // B*N
    dinv[i] = rsqrtf((float)cnt[i] + 1.0f);
}

__global__ __launch_bounds__(256) void k_adj(const int* __restrict__ ei, const float* __restrict__ dinv,
                                             float* __restrict__ AdjF) {
    int idx = blockIdx.x * 256 + threadIdx.x;           // B*E
    int b = idx / EE, e = idx % EE;
    const int* eb = ei + (long)b * 2 * EE;
    int s = eb[e], tg = eb[EE + e];
    // duplicate (s,tg) edges add IDENTICAL values -> order-independent -> deterministic
    atomicAdd(&AdjF[((long)b * NN + tg) * NN + s], dinv[b * NN + tg] * dinv[b * NN + s]);
}

__global__ __launch_bounds__(256) void k_adjself(const float* __restrict__ dinv, float* __restrict__ AdjF) {
    int idx = blockIdx.x * 256 + threadIdx.x;           // B*N
    int b = idx / NN, n = idx % NN;
    float d = dinv[idx];
    atomicAdd(&AdjF[((long)b * NN + n) * NN + n], d * d);
}

// AdjF [b][200][200] f32 -> Adjb [b][256][224] bf16 zero-padded
__global__ __launch_bounds__(256) void k_adjconv(const float* __restrict__ AdjF, bf16* __restrict__ Adjb) {
    long idx = (long)blockIdx.x * 256 + threadIdx.x;    // 256*256*224
    int col = idx % 224;
    int row = (idx / 224) & 255;
    int b = idx / (224 * 256);
    float v = (row < NN && col < NN) ? AdjF[((long)b * NN + row) * NN + col] : 0.f;
    Adjb[idx] = __float2bfloat16(v);
}

// m1t[b][h=256][node k=224] = (node_features @ W1)^T, zero-padded
__global__ __launch_bounds__(256) void k_m1t(const float* __restrict__ nf, const float* __restrict__ W1,
                                             bf16* __restrict__ m1t) {
    long idx = (long)blockIdx.x * 256 + threadIdx.x;    // 256*256*224
    int node = idx % 224;
    int h = (idx / 224) & 255;
    int b = idx / (224 * 256);
    float v = 0.f;
    if (node < NN) {
        const float* x = nf + ((long)b * NN + node) * 4;
        v = x[0] * W1[h] + x[1] * W1[256 + h] + x[2] * W1[512 + h] + x[3] * W1[768 + h];
    }
    m1t[idx] = __float2bfloat16(v);
}

// ---------------- weight conversions ----------------
__global__ __launch_bounds__(256) void k_conv(const float* __restrict__ s, bf16* __restrict__ d, int n) {
    int i = blockIdx.x * 256 + threadIdx.x;
    if (i < n) d[i] = __float2bfloat16(s[i]);
}

__global__ __launch_bounds__(256) void k_convT(const float* __restrict__ W2, bf16* __restrict__ w2t) {
    int i = blockIdx.x * 256 + threadIdx.x;             // 65536: i = n*256+k
    w2t[i] = __float2bfloat16(W2[((i & 255) << 8) + (i >> 8)]);
}

__global__ __launch_bounds__(256) void k_bsum(const float* __restrict__ bih, const float* __restrict__ bhh,
                                              float* __restrict__ bsum) {
    int i = blockIdx.x * 256 + threadIdx.x;             // 10240
    bsum[i] = bih[i] + bhh[i];
}

// ---- weight fragment shuffle: B-frag-contiguous, 16-wave layout ----
// dst[br][jw16][kc8][g4][lane64][8]  from Whh[br*2+layer]
__global__ __launch_bounds__(256) void k_wfrag(const float* __restrict__ Whh, bf16* __restrict__ dst_, int layer) {
    int i = blockIdx.x * 256 + threadIdx.x;             // < 163840
    int lane = i & 63, g = (i >> 6) & 3, kc = (i >> 8) & 7, jw = (i >> 11) & 15, br = i >> 15;
    int row = g * 256 + jw * 16 + (lane & 15);
    int col = kc * 32 + (lane >> 4) * 8;
    const float* src = Whh + (long)(br * 2 + layer) * 262144 + (long)row * 256 + col;
    bf16* dst = dst_ + (long)i * 8;
#pragma unroll
    for (int e = 0; e < 8; ++e) dst[e] = __float2bfloat16(src[e]);
}

// ---------------- MFMA GEMM: C = A @ Bt^T (+bias)(+relu), bf16 in/out, f32 accum ----------
template<int BM, int BN, bool RELU, bool CT>
__global__ __launch_bounds__(256)
void mgemm(const bf16* __restrict__ A, long aBatch, int lda,
           const bf16* __restrict__ Bt, long bBatch, int ldb,
           bf16* __restrict__ C, long cBatch, int ldc,
           const float* __restrict__ bias, long biasBatch,
           int K, int Mvalid)
{
    constexpr int ACH = BM / 16, TCH = BM / 16 + BN / 16, PW = TCH / 4;
    constexpr int FM = BM / 32, FN = BN / 32;
    __shared__ bf16 Al[BM][32];
    __shared__ bf16 Bl[BN][32];
    int bz = blockIdx.z;
    const bf16* Ab = A + (long)bz * aBatch + (long)blockIdx.y * BM * lda;
    const bf16* Bb = Bt + (long)bz * bBatch + (long)blockIdx.x * BN * ldb;
    int tid = threadIdx.x, w = tid >> 6, l = tid & 63;
    int wm = w >> 1, wn = w & 1;
    int lrow = l >> 2, lk8 = (l & 3) * 8;
    f32x4 acc[FM][FN] = {};
    for (int k0 = 0; k0 < K; k0 += 32) {
#pragma unroll
        for (int cc = 0; cc < PW; ++cc) {
            int c = w * PW + cc;
            if (c < ACH) GLOAD16(Ab + (long)(c * 16 + lrow) * lda + k0 + lk8, ((char*)&Al[0][0]) + c * 1024);
            else { int bc = c - ACH; GLOAD16(Bb + (long)(bc * 16 + lrow) * ldb + k0 + lk8, ((char*)&Bl[0][0]) + bc * 1024); }
        }
        __syncthreads();
        bh8 af[FM], bfv[FN];
#pragma unroll
        for (int i = 0; i < FM; ++i) af[i] = *(const bh8*)&Al[wm * (BM / 2) + i * 16 + (l & 15)][(l >> 4) * 8];
#pragma unroll
        for (int j = 0; j < FN; ++j) bfv[j] = *(const bh8*)&Bl[wn * (BN / 2) + j * 16 + (l & 15)][(l >> 4) * 8];
#pragma unroll
        for (int i = 0; i < FM; ++i)
#pragma unroll
            for (int j = 0; j < FN; ++j)
                acc[i][j] = __builtin_amdgcn_mfma_f32_16x16x32_bf16(af[i], bfv[j], acc[i][j], 0, 0, 0);
        __syncthreads();
    }
    bf16* Cb = C + (long)bz * cBatch;
    int mq = blockIdx.y * BM + wm * (BM / 2);
    int nq = blockIdx.x * BN + wn * (BN / 2);
#pragma unroll
    for (int i = 0; i < FM; ++i) {
#pragma unroll
        for (int j = 0; j < FN; ++j) {
            int n = nq + j * 16 + (l & 15);
            float bv = bias ? bias[(long)bz * biasBatch + n] : 0.f;
            int m0 = mq + i * 16 + (l >> 4) * 4;
#pragma unroll
            for (int r = 0; r < 4; ++r) {
                int m = m0 + r;
                if (m < Mvalid) {
                    float v = acc[i][j][r] + bv;
                    if (RELU) v = fmaxf(v, 0.f);
                    if (CT) Cb[(long)n * ldc + m] = __float2bfloat16(v);
                    else    Cb[(long)m * ldc + n] = __float2bfloat16(v);
                }
            }
        }
    }
}

// ============ persistent block-local LSTM layer 0, weight-resident ============
// 80 blocks, XCD-pinned; 1024 thr = 16 waves (4/SIMD -> 128 VGPR budget).
// Weights: kc 0..3 VALUE-pinned in VGPR (64 regs), kc 4..5 in LDS (128 KB),
// kc 6..7 streamed from L2 (128 KB/step/CU).
__global__ __launch_bounds__(1024, 4)
void k_rnn0(const bf16* __restrict__ wfrag0, const bf16* __restrict__ gpart,
            const float* __restrict__ xf, const float* __restrict__ wih0,
            bf16* __restrict__ y0)
{
    extern __shared__ char dyns[];              // [0,131072) weights kc4..5; [131072,147456) hbuf
    char* wlds = dyns;
    char* hbase = dyns + 131072;
    int g_ = 10 * (blockIdx.x & 7) + (blockIdx.x >> 3);   // XCD-pinning permutation
    int btile = g_ & 15, br = g_ >> 4;
    int tid = threadIdx.x, w = tid >> 6, l = tid & 63;
    int ln = l & 15, lg = l >> 4;
    int j = w * 16 + ln;
    const bf16* wb = wfrag0 + ((long)(br * 16 + w)) * 16384 + l * 8;
    // VGPR-resident weights (kc 0..3), VALUE-pinned so reload is illegal
    bh8 wreg[16];
#pragma unroll
    for (int kc = 0; kc < 4; ++kc)
#pragma unroll
        for (int g = 0; g < 4; ++g)
            wreg[kc * 4 + g] = *(const bh8*)(wb + kc * 2048 + g * 512);
#pragma unroll
    for (int i = 0; i < 16; ++i) pin16(&wreg[i]);
    // LDS-resident weights (kc 4..5): lane-linear 16B layout (conflict-free)
#pragma unroll
    for (int f = 0; f < 8; ++f) {
        int kc = 4 + (f >> 2), g = f & 3;
        *(uint4*)(wlds + (w * 8 + f) * 1024 + l * 16) = *(const uint4*)(wb + kc * 2048 + g * 512);
    }
    // packed per-thread constants
    __hip_bfloat162 w01p[4];
    __hip_bfloat162 gpk[8];                     // [g][rpair]
#pragma unroll
    for (int g = 0; g < 4; ++g) {
        const float* wr = wih0 + ((long)br * 1024 + g * 256 + j) * 258;
        w01p[g].x = __float2bfloat16(wr[0]);
        w01p[g].y = __float2bfloat16(wr[1]);
#pragma unroll
        for (int rp = 0; rp < 2; ++rp) {
            int b0 = btile * 16 + lg * 4 + rp * 2;
            __hip_bfloat162 t2;
            t2.x = gpart[((long)br * 256 + b0) * 1024 + g * 256 + j];
            t2.y = gpart[((long)br * 256 + b0 + 1) * 1024 + g * 256 + j];
            gpk[g * 2 + rp] = t2;
        }
    }
    float c[4] = {};
    __syncthreads();
    int pp = 0;
#pragma unroll 1
    for (int t = 0; t < 30; ++t) {
        f32x4 acc[4] = {};
        if (t > 0) {
            const char* hb = hbase + (pp ^ 1) * 8192;
#pragma unroll
            for (int kc = 0; kc < 4; ++kc) {    // VGPR weights
                bh8 a = *(const bh8*)(hb + ln * 512 + ((kc * 64 + lg * 16) ^ ((ln & 7) << 4)));
#pragma unroll
                for (int g = 0; g < 4; ++g)
                    acc[g] = __builtin_amdgcn_mfma_f32_16x16x32_bf16(a, wreg[kc * 4 + g], acc[g], 0, 0, 0);
            }
#pragma unroll
            for (int kc = 4; kc < 6; ++kc) {    // LDS weights
                bh8 a = *(const bh8*)(hb + ln * 512 + ((kc * 64 + lg * 16) ^ ((ln & 7) << 4)));
#pragma unroll
                for (int g = 0; g < 4; ++g) {
                    bh8 wv = *(const bh8*)(wlds + (w * 8 + (kc - 4) * 4 + g) * 1024 + l * 16);
                    acc[g] = __builtin_amdgcn_mfma_f32_16x16x32_bf16(a, wv, acc[g], 0, 0, 0);
                }
            }
#pragma unroll
            for (int kc = 6; kc < 8; ++kc) {    // streamed weights (L2)
                bh8 a = *(const bh8*)(hb + ln * 512 + ((kc * 64 + lg * 16) ^ ((ln & 7) << 4)));
#pragma unroll
                for (int g = 0; g < 4; ++g) {
                    bh8 wv = *(const bh8*)(wb + kc * 2048 + g * 512);
                    acc[g] = __builtin_amdgcn_mfma_f32_16x16x32_bf16(a, wv, acc[g], 0, 0, 0);
                }
            }
        }
        char* hw = hbase + pp * 8192;
        float2 xr[4];
#pragma unroll
        for (int r = 0; r < 4; ++r) {
            int b = btile * 16 + lg * 4 + r;
            xr[r] = *(const float2*)(xf + ((long)(br * 256 + b) * 30 + t) * 2);
        }
#pragma unroll
        for (int r = 0; r < 4; ++r) {
            float z[4];
#pragma unroll
            for (int g = 0; g < 4; ++g) {
                __hip_bfloat162 gp2 = gpk[g * 2 + (r >> 1)];
                float gpv = (r & 1) ? __high2float(gp2) : __low2float(gp2);
                z[g] = acc[g][r] + gpv + xr[r].x * __low2float(w01p[g]) + xr[r].y * __high2float(w01p[g]);
            }
            float ig = 1.f / (1.f + __expf(-z[0]));
            float fg = 1.f / (1.f + __expf(-z[1]));
            float gv = 2.f / (1.f + __expf(-2.f * z[2])) - 1.f;
            float og = 1.f / (1.f + __expf(-z[3]));
            float cv = fg * c[r] + ig * gv;
            c[r] = cv;
            float hv = og * (2.f / (1.f + __expf(-2.f * cv)) - 1.f);
            int row = lg * 4 + r;
            *(bf16*)(hw + row * 512 + ((2 * j) ^ ((row & 7) << 4))) = __float2bfloat16(hv);
        }
        __syncthreads();
        // unswizzling coalesced copy of the h tile -> y0[t] (8 KB, 8 B/thread)
        {
            int row = tid >> 6;
            int off = (tid & 63) * 8;
            uint2 v = *(const uint2*)(hw + row * 512 + (off ^ ((row & 7) << 4)));
            *(uint2*)((char*)y0 + (((long)(br * 30 + t) * 256 + btile * 16 + row) * 512) + off) = v;
        }
        pp ^= 1;
    }
}

// ============ persistent block-local LSTM layer 1, weight-resident (K=256) ============
// zin1 precomputed by mgemm (incl. bias). Same weight residency scheme as k_rnn0.
__global__ __launch_bounds__(1024, 4)
void k_rnn1(const bf16* __restrict__ wfrag1, const bf16* __restrict__ zin1,
            bf16* __restrict__ h1out)
{
    extern __shared__ char dyns[];
    char* wlds = dyns;
    char* hbase = dyns + 131072;
    int g_ = 10 * (blockIdx.x & 7) + (blockIdx.x >> 3);   // XCD-pinning permutation
    int btile = g_ & 15, br = g_ >> 4;
    int tid = threadIdx.x, w = tid >> 6, l = tid & 63;
    int ln = l & 15, lg = l >> 4;
    int j = w * 16 + ln;
    const bf16* wb = wfrag1 + ((long)(br * 16 + w)) * 16384 + l * 8;
    bh8 wreg[16];
#pragma unroll
    for (int kc = 0; kc < 4; ++kc)
#pragma unroll
        for (int g = 0; g < 4; ++g)
            wreg[kc * 4 + g] = *(const bh8*)(wb + kc * 2048 + g * 512);
#pragma unroll
    for (int i = 0; i < 16; ++i) pin16(&wreg[i]);
#pragma unroll
    for (int f = 0; f < 8; ++f) {
        int kc = 4 + (f >> 2), g = f & 3;
        *(uint4*)(wlds + (w * 8 + f) * 1024 + l * 16) = *(const uint4*)(wb + kc * 2048 + g * 512);
    }
    float c[4] = {};
    __syncthreads();
    int pp = 0;
    const bf16* zbr = zin1 + (long)br * 7864320;
#pragma unroll 1
    for (int t = 0; t < 30; ++t) {
        // zin for this step (includes bias) — issued first to hide L2 latency
        float zin[4][4];                                  // [g][r]
#pragma unroll
        for (int r = 0; r < 4; ++r) {
            long mrow = (long)(t * 256 + btile * 16 + lg * 4 + r) * 1024;
#pragma unroll
            for (int g = 0; g < 4; ++g) zin[g][r] = bf2f(zbr[mrow + g * 256 + j]);
        }
        f32x4 acc[4] = {};
        if (t > 0) {
            const char* hb = hbase + (pp ^ 1) * 8192;
#pragma unroll
            for (int kc = 0; kc < 4; ++kc) {
                bh8 a = *(const bh8*)(hb + ln * 512 + ((kc * 64 + lg * 16) ^ ((ln & 7) << 4)));
#pragma unroll
                for (int g = 0; g < 4; ++g)
                    acc[g] = __builtin_amdgcn_mfma_f32_16x16x32_bf16(a, wreg[kc * 4 + g], acc[g], 0, 0, 0);
            }
#pragma unroll
            for (int kc = 4; kc < 6; ++kc) {
                bh8 a = *(const bh8*)(hb + ln * 512 + ((kc * 64 + lg * 16) ^ ((ln & 7) << 4)));
#pragma unroll
                for (int g = 0; g < 4; ++g) {
                    bh8 wv = *(const bh8*)(wlds + (w * 8 + (kc - 4) * 4 + g) * 1024 + l * 16);
                    acc[g] = __builtin_amdgcn_mfma_f32_16x16x32_bf16(a, wv, acc[g], 0, 0, 0);
                }
            }
#pragma unroll
            for (int kc = 6; kc < 8; ++kc) {
                bh8 a = *(const bh8*)(hb + ln * 512 + ((kc * 64 + lg * 16) ^ ((ln & 7) << 4)));
#pragma unroll
                for (int g = 0; g < 4; ++g) {
                    bh8 wv = *(const bh8*)(wb + kc * 2048 + g * 512);
                    acc[g] = __builtin_amdgcn_mfma_f32_16x16x32_bf16(a, wv, acc[g], 0, 0, 0);
                }
            }
        }
        char* hw = hbase + pp * 8192;
#pragma unroll
        for (int r = 0; r < 4; ++r) {
            float z[4];
#pragma unroll
            for (int g = 0; g < 4; ++g) z[g] = acc[g][r] + zin[g][r];
            float ig = 1.f / (1.f + __expf(-z[0]));
            float fg = 1.f / (1.f + __expf(-z[1]));
            float gv = 2.f / (1.f + __expf(-2.f * z[2])) - 1.f;
            float og = 1.f / (1.f + __expf(-z[3]));
            float cv = fg * c[r] + ig * gv;
            c[r] = cv;
            float hv = og * (2.f / (1.f + __expf(-2.f * cv)) - 1.f);
            int row = lg * 4 + r;
            *(bf16*)(hw + row * 512 + ((2 * j) ^ ((row & 7) << 4))) = __float2bfloat16(hv);
            if (t == 29) {
                int b = btile * 16 + row;
                h1out[((long)br * 256 + b) * 256 + j] = __float2bfloat16(hv);
            }
        }
        __syncthreads();
        pp ^= 1;
    }
}

// ---------------- small f32 GEMM (tiny gfeat/gpart) ----------------
template <bool BT, typename TA, typename TB, typename TC>
__global__ __launch_bounds__(256)
void gemm64(const TA* __restrict__ A, long aBatch, int lda,
            const TB* __restrict__ Bm, long bBatch, int ldb,
            TC* __restrict__ C, long cBatch, int ldc,
            const float* __restrict__ bias, long biasBatch,
            int M, int Nn, int K, int flags) {
    __shared__ float As[16][64];
    __shared__ float Bs[16][64];
    int bz = blockIdx.z;
    const TA* Ab = A + (long)bz * aBatch;
    const TB* Bb = Bm + (long)bz * bBatch;
    TC* Cb = C + (long)bz * cBatch;
    int m0 = blockIdx.y * 64, n0 = blockIdx.x * 64;
    int tid = threadIdx.x;
    int tr = tid >> 4, tc = tid & 15;
    float acc[4][4] = {};
    int la_m = tid >> 2;
    int la_k = (tid & 3) * 4;
    for (int k0 = 0; k0 < K; k0 += 16) {
#pragma unroll
        for (int j = 0; j < 4; ++j) {
            int kk = la_k + j;
            float v = 0.f;
            if (m0 + la_m < M && k0 + kk < K) v = ldf(&Ab[(long)(m0 + la_m) * lda + k0 + kk]);
            As[kk][la_m] = v;
        }
        if (!BT) {
            int n = tid & 63, kb = (tid >> 6) * 4;
#pragma unroll
            for (int j = 0; j < 4; ++j) {
                int kk = kb + j;
                float v = 0.f;
                if (k0 + kk < K && n0 + n < Nn) v = ldf(&Bb[(long)(k0 + kk) * ldb + n0 + n]);
                Bs[kk][n] = v;
            }
        } else {
            int n = tid >> 2, kb = (tid & 3) * 4;
#pragma unroll
            for (int j = 0; j < 4; ++j) {
                int kk = kb + j;
                float v = 0.f;
                if (k0 + kk < K && n0 + n < Nn) v = ldf(&Bb[(long)(n0 + n) * ldb + k0 + kk]);
                Bs[kk][n] = v;
            }
        }
        __syncthreads();
#pragma unroll
        for (int kk = 0; kk < 16; ++kk) {
            float4 a4 = *(const float4*)&As[kk][tr * 4];
            float4 b4 = *(const float4*)&Bs[kk][tc * 4];
            float a[4] = {a4.x, a4.y, a4.z, a4.w};
            float bb[4] = {b4.x, b4.y, b4.z, b4.w};
#pragma unroll
            for (int i = 0; i < 4; ++i)
#pragma unroll
                for (int j = 0; j < 4; ++j) acc[i][j] += a[i] * bb[j];
        }
        __syncthreads();
    }
#pragma unroll
    for (int i = 0; i < 4; ++i) {
        int m = m0 + tr * 4 + i;
        if (m >= M) continue;
#pragma unroll
        for (int j = 0; j < 4; ++j) {
            int n = n0 + tc * 4 + j;
            if (n >= Nn) continue;
            float v = acc[i][j];
            if (bias) v += bias[(long)bz * biasBatch + n];
            if (flags & 1) v = fmaxf(v, 0.f);
            stf(&Cb[(long)m * ldc + n], v);
        }
    }
}

// ---------------- MFMA attention, fully reduced to gmean ----------------
__global__ __launch_bounds__(256) void k_attn(const bf16* __restrict__ qkv, float* __restrict__ gmean) {
    int b = blockIdx.x >> 2, hd = blockIdx.x & 3;
    __shared__ bf16 Ks[208][72];
    __shared__ float CSl[4][208];
    __shared__ float Gp[4][64];
    int tid = threadIdx.x, w = tid >> 6, l = tid & 63;
    const bf16* qb = qkv + (long)b * (NN * 768) + hd * 64;
    for (int i = tid; i < 208 * 8; i += 256) {
        int n = i >> 3, g = i & 7;
        uint4 v = make_uint4(0, 0, 0, 0);
        if (n < NN) v = *(const uint4*)(qb + (long)n * 768 + 256 + g * 8);
        *(uint4*)&Ks[n][g * 8] = v;
    }
    __syncthreads();
    float cs[13];
#pragma unroll
    for (int t = 0; t < 13; ++t) cs[t] = 0.f;
    int ln = l & 15, lg = l >> 4;
    for (int qt = w; qt < 13; qt += 4) {
        int qr = qt * 16 + ln; if (qr > NN - 1) qr = NN - 1;
        bh8 aq0 = *(const bh8*)(qb + (long)qr * 768 + lg * 8);
        bh8 aq1 = *(const bh8*)(qb + (long)qr * 768 + 32 + lg * 8);
        f32x4 s[13];
#pragma unroll
        for (int t = 0; t < 13; ++t) s[t] = f32x4{0.f, 0.f, 0.f, 0.f};
#pragma unroll
        for (int t = 0; t < 13; ++t) {
            bh8 b0 = *(const bh8*)&Ks[t * 16 + ln][lg * 8];
            bh8 b1 = *(const bh8*)&Ks[t * 16 + ln][32 + lg * 8];
            s[t] = __builtin_amdgcn_mfma_f32_16x16x32_bf16(aq0, b0, s[t], 0, 0, 0);
            s[t] = __builtin_amdgcn_mfma_f32_16x16x32_bf16(aq1, b1, s[t], 0, 0, 0);
        }
        float mx[4] = {-1e30f, -1e30f, -1e30f, -1e30f};
#pragma unroll
        for (int t = 0; t < 13; ++t) {
            bool vn = (t < 12) | (ln < 8);
#pragma unroll
            for (int r = 0; r < 4; ++r) {
                float v = s[t][r] * 0.125f;
                s[t][r] = v;
                if (vn) mx[r] = fmaxf(mx[r], v);
            }
        }
#pragma unroll
        for (int off = 1; off < 16; off <<= 1)
#pragma unroll
            for (int r = 0; r < 4; ++r) mx[r] = fmaxf(mx[r], __shfl_xor(mx[r], off));
        float sum[4] = {0.f, 0.f, 0.f, 0.f};
#pragma unroll
        for (int t = 0; t < 13; ++t) {
            bool vn = (t < 12) | (ln < 8);
#pragma unroll
            for (int r = 0; r < 4; ++r) {
                float e = vn ? __expf(s[t][r] - mx[r]) : 0.f;
                s[t][r] = e;
                sum[r] += e;
            }
        }
#pragma unroll
        for (int off = 1; off < 16; off <<= 1)
#pragma unroll
            for (int r = 0; r < 4; ++r) sum[r] += __shfl_xor(sum[r], off);
        float inv[4];
#pragma unroll
        for (int r = 0; r < 4; ++r) inv[r] = 1.f / sum[r];
#pragma unroll
        for (int r = 0; r < 4; ++r) {
            int q = qt * 16 + lg * 4 + r;
            if (q < NN) {
#pragma unroll
                for (int t = 0; t < 13; ++t) cs[t] += s[t][r] * inv[r];
            }
        }
    }
#pragma unroll
    for (int t = 0; t < 13; ++t) {
        cs[t] += __shfl_xor(cs[t], 16);
        cs[t] += __shfl_xor(cs[t], 32);
    }
    if (l < 16) {
#pragma unroll
        for (int t = 0; t < 13; ++t) CSl[w][t * 16 + l] = cs[t];
    }
    __syncthreads();
    float part = 0.f;
    for (int n = w * 50; n < w * 50 + 50; ++n) {
        float csn = CSl[0][n] + CSl[1][n] + CSl[2][n] + CSl[3][n];
        part += csn * bf2f(qb[(long)n * 768 + 512 + l]);
    }
    Gp[w][l] = part;
    __syncthreads();
    if (w == 0) {
        float tot = Gp[0][l] + Gp[1][l] + Gp[2][l] + Gp[3][l];
        gmean[b * 256 + hd * 64 + l] = tot * (1.0f / 200.0f);
    }
}

// ---------------- heads ----------------
__global__ __launch_bounds__(256) void k_heads(const bf16* __restrict__ lasth,
                                               const float* __restrict__ fcW_pv, const float* __restrict__ fcb_pv,
                                               const float* __restrict__ fcW_s, const float* __restrict__ fcb_s,
                                               float* __restrict__ out) {
    int b = blockIdx.x;
    __shared__ float hl[5][257];
    for (int idx = threadIdx.x; idx < 5 * 256; idx += 256) {
        int k = idx >> 8, h = idx & 255;
        hl[k][h] = bf2f(lasth[((long)k * 256 + b) * 256 + h]);
    }
    __syncthreads();
    int i = threadIdx.x;
    if (i < 210) {
        int k, o, l, c;
        const float* w;
        float bias;
        bool sig = false;
        if (i < 60)       { k = 0; o = i;       w = fcW_pv + o * 256;        bias = fcb_pv[o];       l = o >> 1; c = o & 1; }
        else if (i < 120) { k = 1; o = i - 60;  w = fcW_pv + (60 + o) * 256; bias = fcb_pv[60 + o];  l = o >> 1; c = 2 + (o & 1); }
        else if (i < 150) { k = 2; o = i - 120; w = fcW_s + o * 256;         bias = fcb_s[o];        l = o; c = 4; }
        else if (i < 180) { k = 3; o = i - 150; w = fcW_s + (30 + o) * 256;  bias = fcb_s[30 + o];   l = o; c = 5; sig = true; }
        else              { k = 4; o = i - 180; w = fcW_s + (60 + o) * 256;  bias = fcb_s[60 + o];   l = o; c = 6; sig = true; }
        float acc = bias;
        for (int h = 0; h < 256; ++h) acc += hl[k][h] * w[h];
        if (sig) acc = 1.f / (1.f + __expf(-acc));
        out[(long)b * 210 + l * 7 + c] = acc;
    }
}

// ---------------- launch ----------------
extern "C" void kernel_launch(void* const* d_in, const int* in_sizes, int n_in,
                              void* d_out, int out_size, void* d_ws, size_t ws_size,
                              hipStream_t stream) {
    (void)in_sizes; (void)n_in;
    const float* x_feats   = (const float*)d_in[0];
    const float* node_feat = (const float*)d_in[1];
    const int*   edge_idx  = (const int*)d_in[2];
    const float* gcn_W1    = (const float*)d_in[3];
    const float* gcn_b1    = (const float*)d_in[4];
    const float* gcn_W2    = (const float*)d_in[5];
    const float* gcn_b2    = (const float*)d_in[6];
    const float* attn_in_w = (const float*)d_in[7];
    const float* attn_in_b = (const float*)d_in[8];
    const float* attn_out_w= (const float*)d_in[9];
    const float* attn_out_b= (const float*)d_in[10];
    const float* Wih0      = (const float*)d_in[11];
    const float* Wih1      = (const float*)d_in[12];
    const float* Whh       = (const float*)d_in[13];
    const float* bih       = (const float*)d_in[14];
    const float* bhh       = (const float*)d_in[15];
    const float* fcW_pv    = (const float*)d_in[16];
    const float* fcb_pv    = (const float*)d_in[17];
    const float* fcW_s     = (const float*)d_in[18];
    const float* fcb_s     = (const float*)d_in[19];
    float* out = (float*)d_out;

    const size_t NEEDED = 186966016ULL;
    if (ws_size < NEEDED) {
        k_diag<<<210, 256, 0, stream>>>(out, out_size, (float)(ws_size >> 20));
        return;
    }
    char* base = (char*)d_ws;
    bf16*  Adjb  = (bf16*)(base + 0);            // [256][256][224]
    bf16*  y0    = (bf16*)(base + 0);            // [5][30][256][256] plain rows (Adjb dead)
    bf16*  m1t   = (bf16*)(base + 29360128);     // [256][256][224] (later m2t)
    bf16*  m2t   = m1t;
    bf16*  actp  = (bf16*)(base + 58720256);     // [256][256][256] (h1p -> gp)
    char*  bigb  = base + 92274688;              // AdjF f32 -> qkv -> zin1
    float* AdjF  = (float*)bigb;
    bf16*  qkv   = (bf16*)bigb;
    bf16*  zin1  = (bf16*)bigb;                  // [5][7680][1024]
    bf16*  w2t   = (bf16*)(base + 170917888);
    bf16*  aiwb  = (bf16*)(base + 171048960);
    bf16*  wih1b = (bf16*)(base + 171442176);
    bf16*  wfrag0= (bf16*)(base + 174063616);
    bf16*  wfrag1= (bf16*)(base + 176685056);
    bf16*  gpart = (bf16*)(base + 179306496);
    float* dinv  = (float*)(base + 181927936);
    int*   degc  = (int*)(base + 182132736);
    float* gmean = (float*)(base + 182337536);
    float* gfeat = (float*)(base + 182599680);
    float* bsum  = (float*)(base + 182861824);
    bf16*  h1b   = (bf16*)(base + 186310656);

    hipMemsetAsync(AdjF, 0, 40960000, stream);
    hipMemsetAsync(degc, 0, 204800, stream);

    k_deg<<<1600, 256, 0, stream>>>(edge_idx, degc);
    k_dinv<<<200, 256, 0, stream>>>(degc, dinv);
    k_adj<<<1600, 256, 0, stream>>>(edge_idx, dinv, AdjF);
    k_adjself<<<200, 256, 0, stream>>>(dinv, AdjF);
    k_adjconv<<<57344, 256, 0, stream>>>(AdjF, Adjb);
    k_m1t<<<57344, 256, 0, stream>>>(node_feat, gcn_W1, m1t);

    k_convT<<<256, 256, 0, stream>>>(gcn_W2, w2t);
    k_conv<<<768, 256, 0, stream>>>(attn_in_w, aiwb, 196608);
    k_conv<<<5120, 256, 0, stream>>>(Wih1, wih1b, 1310720);
    k_wfrag<<<640, 256, 0, stream>>>(Whh, wfrag0, 0);
    k_wfrag<<<640, 256, 0, stream>>>(Whh, wfrag1, 1);
    k_bsum<<<40, 256, 0, stream>>>(bih, bhh, bsum);

    mgemm<128, 128, true, false><<<dim3(2, 2, 256), 256, 0, stream>>>(
        Adjb, 57344, 224, m1t, 57344, 224, actp, 65536, 256, gcn_b1, 0, 224, 256);
    mgemm<128, 128, false, true><<<dim3(2, 2, 256), 256, 0, stream>>>(
        actp, 65536, 256, w2t, 0, 256, m2t, 57344, 224, nullptr, 0, 256, 200);
    mgemm<128, 128, true, false><<<dim3(2, 2, 256), 256, 0, stream>>>(
        Adjb, 57344, 224, m2t, 57344, 224, actp, 65536, 256, gcn_b2, 0, 224, 256);
    mgemm<128, 128, false, false><<<dim3(6, 2, 256), 256, 0, stream>>>(
        actp, 65536, 256, aiwb, 0, 256, qkv, 153600, 768, attn_in_b, 0, 256, 200);

    k_attn<<<1024, 256, 0, stream>>>(qkv, gmean);
    gemm64<true, float, float, float><<<dim3(4, 4, 1), 256, 0, stream>>>(
        gmean, 0, 256, attn_out_w, 0, 256, gfeat, 0, 256, attn_out_b, 0, 256, 256, 256, 0);
    gemm64<true, float, float, bf16><<<dim3(16, 4, 5), 256, 0, stream>>>(
        gfeat, 0, 256, Wih0 + 2, 264192, 258, gpart, 262144, 1024, bsum, 2048, 256, 1024, 256, 0);

    // weight-resident persistent LSTM layers (147456 B dynamic LDS each)
    hipFuncSetAttribute((const void*)k_rnn0, hipFuncAttributeMaxDynamicSharedMemorySize, 147456);
    hipFuncSetAttribute((const void*)k_rnn1, hipFuncAttributeMaxDynamicSharedMemorySize, 147456);
    k_rnn0<<<80, 1024, 147456, stream>>>(wfrag0, gpart, x_feats, Wih0, y0);
    mgemm<128, 128, false, false><<<dim3(8, 60, 5), 256, 0, stream>>>(
        y0, 1966080, 256, wih1b, 262144, 256, zin1, 7864320, 1024, bsum + 1024, 2048, 256, 7680);
    k_rnn1<<<80, 1024, 147456, stream>>>(wfrag1, zin1, h1b);
    k_heads<<<256, 256, 0, stream>>>(h1b, fcW_pv, fcb_pv, fcW_s, fcb_s, out);
}